// Round 4
// baseline (349.259 us; speedup 1.0000x reference)
//
#include <hip/hip_runtime.h>

// x (N,S,C,V) = (8,2048,4,64) fp32; embedding (C,K,V) = (4,512,64) fp32.
#define NROW 16384   // N*S
#define CCH  4
#define KCB  512
#define VDIM 64
#define ZW   8       // waves per block = K-chunks; each wave scans KCB/ZW = 64 codes

// Pre-kernel: e2[c*K+k] = sum_v emb[c][k][v]^2  (2048 floats into d_ws)
__global__ void e2_kernel(const float* __restrict__ emb, float* __restrict__ e2) {
    int i = blockIdx.x * blockDim.x + threadIdx.x;
    if (i >= CCH * KCB) return;
    const float* e = emb + (size_t)i * VDIM;
    float s = 0.f;
#pragma unroll
    for (int v = 0; v < VDIM; ++v) s = fmaf(e[v], e[v], s);
    e2[i] = s;
}

// Block = (64 rows, ZW K-chunks) = 512 threads, 8 waves; c = blockIdx.y.
// Per wave: 64 codes in 4 groups of 16. acc[16] + 16-float x chunk + 16
// transient e floats ≈ 60 live VGPRs -> honest fit at the compiler's 8-wave
// 64-VGPR occupancy target (no AGPR shuffling, no remat of big arrays).
// Embedding arrives via wave-uniform global_load_dwordx4 (HW broadcast),
// 1 VMEM instr per 4 FMA instr, freely pipelined by the compiler.
__global__ __launch_bounds__(512)
void vq_kernel(const float* __restrict__ x, const float* __restrict__ emb,
               const float* __restrict__ e2w, float* __restrict__ out) {
    const int lane = threadIdx.x;     // row within 64-row tile
    const int c = blockIdx.y;         // uniform channel
    const int z = threadIdx.y;        // wave-uniform K-chunk (blockDim.x == 64)
    const int r = blockIdx.x * 64 + lane;

    const float4* xp = (const float4*)(x + ((size_t)r * CCH + c) * VDIM);

    // x2 = sum x^2 (streaming; x chunks stay L1-hot for the loop re-reads)
    float x2 = 0.f;
#pragma unroll
    for (int i = 0; i < 16; ++i) {
        const float4 t = xp[i];
        x2 = fmaf(t.x, t.x, x2); x2 = fmaf(t.y, t.y, x2);
        x2 = fmaf(t.z, t.z, x2); x2 = fmaf(t.w, t.w, x2);
    }

    const float* eb  = emb + (size_t)c * (KCB * VDIM);  // wave-uniform base
    const float* e2c = e2w + (size_t)c * KCB;
    const int kbase = z * (KCB / ZW);

    float best = 3.4e38f;
    int bk = kbase;

#pragma unroll
    for (int g = 0; g < 4; ++g) {                 // 4 groups of 16 codes
        const int k0 = kbase + g * 16;
        float acc[16];
#pragma unroll
        for (int t = 0; t < 16; ++t) acc[t] = 0.f;

#pragma unroll
        for (int vc = 0; vc < 4; ++vc) {          // 4 v-chunks of 16
            const float4 xa = xp[vc * 4 + 0];     // 16 x floats (L1-hot)
            const float4 xb = xp[vc * 4 + 1];
            const float4 xc = xp[vc * 4 + 2];
            const float4 xd = xp[vc * 4 + 3];
#pragma unroll
            for (int t = 0; t < 16; ++t) {
                const float4* ep = (const float4*)(eb + (size_t)(k0 + t) * VDIM + vc * 16);
                const float4 e0 = ep[0];          // wave-uniform -> broadcast
                const float4 e1 = ep[1];
                const float4 e2_ = ep[2];
                const float4 e3 = ep[3];
                float a = acc[t];
                a = fmaf(e0.x, xa.x, a); a = fmaf(e0.y, xa.y, a);
                a = fmaf(e0.z, xa.z, a); a = fmaf(e0.w, xa.w, a);
                a = fmaf(e1.x, xb.x, a); a = fmaf(e1.y, xb.y, a);
                a = fmaf(e1.z, xb.z, a); a = fmaf(e1.w, xb.w, a);
                a = fmaf(e2_.x, xc.x, a); a = fmaf(e2_.y, xc.y, a);
                a = fmaf(e2_.z, xc.z, a); a = fmaf(e2_.w, xc.w, a);
                a = fmaf(e3.x, xd.x, a); a = fmaf(e3.y, xd.y, a);
                a = fmaf(e3.z, xd.z, a); a = fmaf(e3.w, xd.w, a);
                acc[t] = a;
            }
        }

        // distances: exact reference expression/order (x2 - 2*xe) + e2
        const float4* e2p = (const float4*)(e2c + k0);
        const float4 q0 = e2p[0], q1 = e2p[1], q2 = e2p[2], q3 = e2p[3];
        const float e2v[16] = { q0.x,q0.y,q0.z,q0.w, q1.x,q1.y,q1.z,q1.w,
                                q2.x,q2.y,q2.z,q2.w, q3.x,q3.y,q3.z,q3.w };
#pragma unroll
        for (int t = 0; t < 16; ++t) {
            const float d = (x2 - 2.0f * acc[t]) + e2v[t];
            if (d < best) { best = d; bk = k0 + t; }   // first-min tie-break
        }
    }

    // Combine ZW partial argmins (z ascending, strict < => global first-min)
    __shared__ float sd[ZW][64];
    __shared__ int   sk[ZW][64];
    sd[z][lane] = best;
    sk[z][lane] = bk;
    __syncthreads();

    if (z == 0) {
#pragma unroll
        for (int w = 1; w < ZW; ++w) {
            const float dw = sd[w][lane];
            const int   kw = sk[w][lane];
            if (dw < best) { best = dw; bk = kw; }
        }

        const float4* ep = (const float4*)(eb + (size_t)bk * VDIM);
        float4* o0 = (float4*)(out + ((size_t)r * CCH + c) * VDIM);
        float s = 0.f;
#pragma unroll
        for (int i = 0; i < 16; ++i) {
            const float4 e4 = ep[i];
            const float4 t = xp[i];           // L2-hot reload
            float4 w;
            // out0 = (output - x) + x, exactly as reference
            w.x = (e4.x - t.x) + t.x;
            w.y = (e4.y - t.y) + t.y;
            w.z = (e4.z - t.z) + t.z;
            w.w = (e4.w - t.w) + t.w;
            o0[i] = w;
            float dx;
            dx = t.x - e4.x; s = fmaf(dx, dx, s);
            dx = t.y - e4.y; s = fmaf(dx, dx, s);
            dx = t.z - e4.z; s = fmaf(dx, dx, s);
            dx = t.w - e4.w; s = fmaf(dx, dx, s);
        }
        const size_t base1 = (size_t)NROW * CCH * VDIM;
        const size_t base2 = base1 + (size_t)NROW * CCH;
        const size_t idx = (size_t)r * CCH + c;
        out[base1 + idx] = s;   // out1
        out[base2 + idx] = s;   // out2 (identical by construction)
    }
}

extern "C" void kernel_launch(void* const* d_in, const int* in_sizes, int n_in,
                              void* d_out, int out_size, void* d_ws, size_t ws_size,
                              hipStream_t stream) {
    const float* x   = (const float*)d_in[0];
    const float* emb = (const float*)d_in[1];
    float* out = (float*)d_out;
    float* e2w = (float*)d_ws;   // 8 KiB

    e2_kernel<<<dim3((CCH * KCB + 255) / 256), dim3(256), 0, stream>>>(emb, e2w);
    vq_kernel<<<dim3(NROW / 64, CCH), dim3(64, ZW), 0, stream>>>(x, emb, e2w, out);
}

// Round 5
// 143.782 us; speedup vs baseline: 2.4291x; 2.4291x over previous
//
#include <hip/hip_runtime.h>

// x (N,S,C,V) = (8,2048,4,64) fp32; embedding (C,K,V) = (4,512,64) fp32.
#define NROW 16384   // N*S
#define CCH  4
#define KCB  512
#define VDIM 64

typedef __attribute__((ext_vector_type(8))) short  short8;   // 8 x bf16 (4 VGPRs)
typedef __attribute__((ext_vector_type(4))) float  floatx4;  // MFMA acc

// round-to-nearest-even fp32 -> bf16 (returns bits), rem = v - bf16(v)
__device__ inline unsigned short bf16h(float v, float* rem) {
    unsigned u = __float_as_uint(v);
    unsigned r = u + 0x7FFFu + ((u >> 16) & 1u);
    unsigned short h = (unsigned short)(r >> 16);
    *rem = v - __uint_as_float((unsigned)h << 16);
    return h;
}

// Pre-pass 1: x (fp32) -> xh, xl (bf16 hi/lo). 1,048,576 float4s.
__global__ void conv_x(const float4* __restrict__ x,
                       ushort4* __restrict__ xh, ushort4* __restrict__ xl) {
    const int i = blockIdx.x * 256 + threadIdx.x;
    const float4 t = x[i];
    float r; float dummy;
    ushort4 h, l;
    h.x = bf16h(t.x, &r); l.x = bf16h(r, &dummy);
    h.y = bf16h(t.y, &r); l.y = bf16h(r, &dummy);
    h.z = bf16h(t.z, &r); l.z = bf16h(r, &dummy);
    h.w = bf16h(t.w, &r); l.w = bf16h(r, &dummy);
    xh[i] = h; xl[i] = l;
}

// Pre-pass 2: emb -> eh, el (bf16 hi/lo) + e2 (fp32). 2048 code rows.
__global__ void conv_e(const float* __restrict__ emb,
                       unsigned short* __restrict__ eh, unsigned short* __restrict__ el,
                       float* __restrict__ e2) {
    const int i = blockIdx.x * 256 + threadIdx.x;   // (c*KCB + k), 2048 total
    const float* e = emb + (size_t)i * VDIM;
    unsigned short* ph = eh + (size_t)i * VDIM;
    unsigned short* pl = el + (size_t)i * VDIM;
    float s = 0.f;
#pragma unroll
    for (int v = 0; v < VDIM; ++v) {
        const float ev = e[v];
        s = fmaf(ev, ev, s);
        float r, dummy;
        ph[v] = bf16h(ev, &r);
        pl[v] = bf16h(r, &dummy);
    }
    e2[i] = s;
}

// Main: per wave, 16 rows x all 512 codes for one channel c via MFMA 16x16x32
// bf16 with hi/lo split (xh*eh + xh*el + xl*eh -> ~2^-17 relative on xe).
// argmin uses d' = e2 - 2*xe (x2 is row-constant -> drops out of argmin).
// A-frag layout: A[m=lane&15][k=(lane>>4)*8+j] (m118/m120-verified);
// B-frag symmetric from row-major E[code][k] (the "B^T input" scheme, m92);
// C/D: col=lane&15, row=(lane>>4)*4+reg (m89-verified).
__global__ __launch_bounds__(256, 4)
void vq_mfma(const unsigned short* __restrict__ xh, const unsigned short* __restrict__ xl,
             const unsigned short* __restrict__ eh, const unsigned short* __restrict__ el,
             const float* __restrict__ e2w, const float* __restrict__ x,
             const float* __restrict__ emb, float* __restrict__ out) {
    const int lane  = threadIdx.x & 63;
    const int wave  = threadIdx.x >> 6;
    const int c     = blockIdx.y;
    const int rbase = blockIdx.x * 64 + wave * 16;
    const int m     = lane & 15;     // row within A-tile / code within B-tile
    const int quad  = lane >> 4;

    // A fragments (resident all loop): rows rbase..rbase+15, k = 0..63, hi+lo
    const size_t arow = ((size_t)(rbase + m) * CCH + c) * VDIM + quad * 8;
    const short8 ah0 = *(const short8*)(xh + arow);
    const short8 ah1 = *(const short8*)(xh + arow + 32);
    const short8 al0 = *(const short8*)(xl + arow);
    const short8 al1 = *(const short8*)(xl + arow + 32);

    const size_t ebase = (size_t)c * KCB * VDIM;
    const float* e2c = e2w + (size_t)c * KCB;

    float bd[4]  = {3.4e38f, 3.4e38f, 3.4e38f, 3.4e38f};
    int   bkk[4] = {0, 0, 0, 0};

    for (int tb = 0; tb < KCB; tb += 16) {          // 32 code-tiles, ascending
        const size_t brow = ebase + (size_t)(tb + m) * VDIM + quad * 8;
        const short8 bh0 = *(const short8*)(eh + brow);
        const short8 bh1 = *(const short8*)(eh + brow + 32);
        const short8 bl0 = *(const short8*)(el + brow);
        const short8 bl1 = *(const short8*)(el + brow + 32);
        const float e2v = e2c[tb + m];

        floatx4 acc = {0.f, 0.f, 0.f, 0.f};
        acc = __builtin_amdgcn_mfma_f32_16x16x32_bf16(ah0, bh0, acc, 0, 0, 0);
        acc = __builtin_amdgcn_mfma_f32_16x16x32_bf16(ah1, bh1, acc, 0, 0, 0);
        acc = __builtin_amdgcn_mfma_f32_16x16x32_bf16(ah0, bl0, acc, 0, 0, 0);
        acc = __builtin_amdgcn_mfma_f32_16x16x32_bf16(ah1, bl1, acc, 0, 0, 0);
        acc = __builtin_amdgcn_mfma_f32_16x16x32_bf16(al0, bh0, acc, 0, 0, 0);
        acc = __builtin_amdgcn_mfma_f32_16x16x32_bf16(al1, bh1, acc, 0, 0, 0);

        const int code = tb + m;
#pragma unroll
        for (int j = 0; j < 4; ++j) {               // 4 rows held by this lane
            const float dj = fmaf(-2.0f, acc[j], e2v);
            if (dj < bd[j]) { bd[j] = dj; bkk[j] = code; }  // strict < = first-min
        }
    }

    // cross-lane argmin over the 16 lanes of each quad (same 4 rows);
    // tie -> lower code index (matches reference first-occurrence)
#pragma unroll
    for (int j = 0; j < 4; ++j) {
        float d = bd[j]; int k = bkk[j];
#pragma unroll
        for (int mask = 1; mask < 16; mask <<= 1) {
            const float od = __shfl_xor(d, mask, 64);
            const int   ok = __shfl_xor(k, mask, 64);
            if (od < d || (od == d && ok < k)) { d = od; k = ok; }
        }
        bd[j] = d; bkk[j] = k;
    }

    // Epilogue: exact fp32 from original x and emb (argmin only came from MFMA)
    const size_t base1 = (size_t)NROW * CCH * VDIM;
    const size_t base2 = base1 + (size_t)NROW * CCH;
#pragma unroll
    for (int j = 0; j < 4; ++j) {
        const int row  = rbase + quad * 4 + j;
        const int code = bkk[j];                    // uniform within quad
        const float4 t  = ((const float4*)(x   + ((size_t)row * CCH + c) * VDIM))[m];
        const float4 e4 = ((const float4*)(emb + (ebase + (size_t)code * VDIM)))[m];
        float4 w;
        w.x = (e4.x - t.x) + t.x;                   // out0 = (output - x) + x
        w.y = (e4.y - t.y) + t.y;
        w.z = (e4.z - t.z) + t.z;
        w.w = (e4.w - t.w) + t.w;
        ((float4*)(out + ((size_t)row * CCH + c) * VDIM))[m] = w;
        float s = 0.f, dx;
        dx = t.x - e4.x; s = fmaf(dx, dx, s);
        dx = t.y - e4.y; s = fmaf(dx, dx, s);
        dx = t.z - e4.z; s = fmaf(dx, dx, s);
        dx = t.w - e4.w; s = fmaf(dx, dx, s);
        s += __shfl_xor(s, 1, 64);
        s += __shfl_xor(s, 2, 64);
        s += __shfl_xor(s, 4, 64);
        s += __shfl_xor(s, 8, 64);
        if (m == 0) {
            const size_t idx = (size_t)row * CCH + c;
            out[base1 + idx] = s;                   // out1
            out[base2 + idx] = s;                   // out2 (identical in reference)
        }
    }
}

extern "C" void kernel_launch(void* const* d_in, const int* in_sizes, int n_in,
                              void* d_out, int out_size, void* d_ws, size_t ws_size,
                              hipStream_t stream) {
    const float* x   = (const float*)d_in[0];
    const float* emb = (const float*)d_in[1];
    float* out = (float*)d_out;

    // ws layout (17.3 MB): xh | xl | eh | el | e2
    unsigned short* xh = (unsigned short*)d_ws;                     // 4,194,304
    unsigned short* xl = xh + (size_t)NROW * CCH * VDIM;            // 4,194,304
    unsigned short* eh = xl + (size_t)NROW * CCH * VDIM;            //   131,072
    unsigned short* el = eh + (size_t)CCH * KCB * VDIM;             //   131,072
    float*          e2 = (float*)(el + (size_t)CCH * KCB * VDIM);   //     2,048

    conv_x<<<dim3(4096), dim3(256), 0, stream>>>((const float4*)x,
                                                 (ushort4*)xh, (ushort4*)xl);
    conv_e<<<dim3(8), dim3(256), 0, stream>>>(emb, eh, el, e2);
    vq_mfma<<<dim3(NROW / 64, CCH), dim3(256), 0, stream>>>(xh, xl, eh, el,
                                                            e2, x, emb, out);
}

// Round 6
// 99.996 us; speedup vs baseline: 3.4927x; 1.4379x over previous
//
#include <hip/hip_runtime.h>

// x (N,S,C,V) = (8,2048,4,64) fp32; embedding (C,K,V) = (4,512,64) fp32.
#define NROW 16384   // N*S
#define CCH  4
#define KCB  512
#define VDIM 64

typedef __attribute__((ext_vector_type(8))) short  short8;   // 8 x bf16 (4 VGPRs)
typedef __attribute__((ext_vector_type(4))) float  floatx4;  // MFMA acc

// round-to-nearest-even fp32 -> bf16 bits; rem = v - bf16(v)
__device__ inline unsigned short bf16h(float v, float* rem) {
    unsigned u = __float_as_uint(v);
    unsigned r = u + 0x7FFFu + ((u >> 16) & 1u);
    unsigned short h = (unsigned short)(r >> 16);
    *rem = v - __uint_as_float((unsigned)h << 16);
    return h;
}

// Single fused kernel. Block = 256 thr (4 waves), grid = (NROW/128, CCH).
// Wave w owns rows [blockIdx.x*128 + w*32, +32) of channel c, scans all 512
// codes. B (codebook) is converted fp32->bf16 hi/lo per 16-code tile and
// staged in LDS ([k-octet][code] layout: frag ds_read_b128 is 2-way = free),
// double-buffered, one barrier per tile; all 4 waves share each tile (4x
// reuse) and each wave runs 2 row-groups (2x reuse + 2 independent MFMA
// chains). A-frags converted inline from x (read-once). argmin uses
// d' = e2 - 2*xe (x2 row-constant, drops out); exact fp32 epilogue.
__global__ __launch_bounds__(256, 2)
void vq_fused(const float* __restrict__ x, const float* __restrict__ emb,
              float* __restrict__ out) {
    __shared__ unsigned short btile[2][2048];  // [dbuf][hi 1024 ush | lo 1024]
    __shared__ float e2s[KCB];

    const int tid  = threadIdx.x;
    const int lane = tid & 63;
    const int m    = lane & 15;
    const int quad = lane >> 4;
    const int wave = tid >> 6;
    const int c    = blockIdx.y;
    const int rbase = blockIdx.x * 128 + wave * 32;

    const float* embc = emb + (size_t)c * (KCB * VDIM);

    // --- startup: e2 for all 512 codes (2 codes/thread) ---
    for (int cc = tid; cc < KCB; cc += 256) {
        const float4* ep = (const float4*)(embc + (size_t)cc * VDIM);
        float s = 0.f;
#pragma unroll
        for (int i = 0; i < 16; ++i) {
            const float4 t = ep[i];
            s = fmaf(t.x, t.x, s); s = fmaf(t.y, t.y, s);
            s = fmaf(t.z, t.z, s); s = fmaf(t.w, t.w, s);
        }
        e2s[cc] = s;
    }

    // --- A fragments: 2 row-groups x 2 k-halves, hi+lo, from fp32 x ---
    short8 ah[2][2], al[2][2];
#pragma unroll
    for (int g = 0; g < 2; ++g) {
        const int row = rbase + g * 16 + m;
        const float4* xr = (const float4*)(x + ((size_t)row * CCH + c) * VDIM);
#pragma unroll
        for (int h = 0; h < 2; ++h) {            // k = h*32 + quad*8 + j
            const float4 f0 = xr[h * 8 + quad * 2];
            const float4 f1 = xr[h * 8 + quad * 2 + 1];
            const float fv[8] = {f0.x, f0.y, f0.z, f0.w, f1.x, f1.y, f1.z, f1.w};
            short8 hh, ll;
#pragma unroll
            for (int j = 0; j < 8; ++j) {
                float r, d;
                hh[j] = (short)bf16h(fv[j], &r);
                ll[j] = (short)bf16h(r, &d);
            }
            ah[g][h] = hh; al[g][h] = ll;
        }
    }

    // --- stage tile 0 (thread i: code=i>>4, float4 f4=i&15 -> koct=f4>>1) ---
    {
        const float4 t0 = ((const float4*)embc)[tid];
        const int code = tid >> 4, f4 = tid & 15;
        ushort4 h4, l4; float r, d;
        h4.x = bf16h(t0.x, &r); l4.x = bf16h(r, &d);
        h4.y = bf16h(t0.y, &r); l4.y = bf16h(r, &d);
        h4.z = bf16h(t0.z, &r); l4.z = bf16h(r, &d);
        h4.w = bf16h(t0.w, &r); l4.w = bf16h(r, &d);
        const int off = (f4 >> 1) * 128 + code * 8 + (f4 & 1) * 4;  // ushorts
        *(ushort4*)&btile[0][off]        = h4;
        *(ushort4*)&btile[0][1024 + off] = l4;
    }
    __syncthreads();

    float bd[2][4]; int bkk[2][4];
#pragma unroll
    for (int g = 0; g < 2; ++g)
#pragma unroll
        for (int j = 0; j < 4; ++j) { bd[g][j] = 3.4e38f; bkk[g][j] = 0; }

    for (int t = 0; t < KCB / 16; ++t) {         // 32 tiles, ascending codes
        const int cur = t & 1;
        // prefetch next tile's fp32 (issued before compute -> latency hidden)
        float4 nt;
        if (t < 31) nt = ((const float4*)(embc + (size_t)(t + 1) * 16 * VDIM))[tid];

        // B frags from LDS: [koct][code] -> bank-conflict-free
        const unsigned short* bt = btile[cur];
        const short8 bh0 = *(const short8*)&bt[      quad * 128 + m * 8];
        const short8 bh1 = *(const short8*)&bt[(4 + quad) * 128 + m * 8];
        const short8 bl0 = *(const short8*)&bt[1024 +       quad * 128 + m * 8];
        const short8 bl1 = *(const short8*)&bt[1024 + (4 + quad) * 128 + m * 8];
        const float e2v = e2s[t * 16 + m];

        floatx4 acc0 = {0.f, 0.f, 0.f, 0.f}, acc1 = {0.f, 0.f, 0.f, 0.f};
        acc0 = __builtin_amdgcn_mfma_f32_16x16x32_bf16(ah[0][0], bh0, acc0, 0, 0, 0);
        acc1 = __builtin_amdgcn_mfma_f32_16x16x32_bf16(ah[1][0], bh0, acc1, 0, 0, 0);
        acc0 = __builtin_amdgcn_mfma_f32_16x16x32_bf16(ah[0][1], bh1, acc0, 0, 0, 0);
        acc1 = __builtin_amdgcn_mfma_f32_16x16x32_bf16(ah[1][1], bh1, acc1, 0, 0, 0);
        acc0 = __builtin_amdgcn_mfma_f32_16x16x32_bf16(ah[0][0], bl0, acc0, 0, 0, 0);
        acc1 = __builtin_amdgcn_mfma_f32_16x16x32_bf16(ah[1][0], bl0, acc1, 0, 0, 0);
        acc0 = __builtin_amdgcn_mfma_f32_16x16x32_bf16(ah[0][1], bl1, acc0, 0, 0, 0);
        acc1 = __builtin_amdgcn_mfma_f32_16x16x32_bf16(ah[1][1], bl1, acc1, 0, 0, 0);
        acc0 = __builtin_amdgcn_mfma_f32_16x16x32_bf16(al[0][0], bh0, acc0, 0, 0, 0);
        acc1 = __builtin_amdgcn_mfma_f32_16x16x32_bf16(al[1][0], bh0, acc1, 0, 0, 0);
        acc0 = __builtin_amdgcn_mfma_f32_16x16x32_bf16(al[0][1], bh1, acc0, 0, 0, 0);
        acc1 = __builtin_amdgcn_mfma_f32_16x16x32_bf16(al[1][1], bh1, acc1, 0, 0, 0);

        const int code = t * 16 + m;
#pragma unroll
        for (int j = 0; j < 4; ++j) {
            const float d0 = fmaf(-2.0f, acc0[j], e2v);
            const float d1 = fmaf(-2.0f, acc1[j], e2v);
            if (d0 < bd[0][j]) { bd[0][j] = d0; bkk[0][j] = code; }
            if (d1 < bd[1][j]) { bd[1][j] = d1; bkk[1][j] = code; }
        }

        // convert + write next tile into the other buffer
        if (t < 31) {
            const int codew = tid >> 4, f4 = tid & 15;
            ushort4 h4, l4; float r, d;
            h4.x = bf16h(nt.x, &r); l4.x = bf16h(r, &d);
            h4.y = bf16h(nt.y, &r); l4.y = bf16h(r, &d);
            h4.z = bf16h(nt.z, &r); l4.z = bf16h(r, &d);
            h4.w = bf16h(nt.w, &r); l4.w = bf16h(r, &d);
            const int off = (f4 >> 1) * 128 + codew * 8 + (f4 & 1) * 4;
            *(ushort4*)&btile[cur ^ 1][off]        = h4;
            *(ushort4*)&btile[cur ^ 1][1024 + off] = l4;
        }
        __syncthreads();   // next tile staged AND everyone done with cur
    }

    // within-quad (16-lane) argmin; tie -> lower code (first-occurrence)
#pragma unroll
    for (int g = 0; g < 2; ++g)
#pragma unroll
    for (int j = 0; j < 4; ++j) {
        float d = bd[g][j]; int k = bkk[g][j];
#pragma unroll
        for (int mask = 1; mask < 16; mask <<= 1) {
            const float od = __shfl_xor(d, mask, 64);
            const int   ok = __shfl_xor(k, mask, 64);
            if (od < d || (od == d && ok < k)) { d = od; k = ok; }
        }
        bd[g][j] = d; bkk[g][j] = k;
    }

    // Epilogue: exact fp32 from original x and emb
    const size_t base1 = (size_t)NROW * CCH * VDIM;
    const size_t base2 = base1 + (size_t)NROW * CCH;
#pragma unroll
    for (int g = 0; g < 2; ++g)
#pragma unroll
    for (int j = 0; j < 4; ++j) {
        const int row  = rbase + g * 16 + quad * 4 + j;
        const int code = bkk[g][j];                 // uniform within quad
        const float4 t4 = ((const float4*)(x + ((size_t)row * CCH + c) * VDIM))[m];
        const float4 e4 = ((const float4*)(embc + (size_t)code * VDIM))[m];
        float4 w;
        w.x = (e4.x - t4.x) + t4.x;                 // out0 = (output - x) + x
        w.y = (e4.y - t4.y) + t4.y;
        w.z = (e4.z - t4.z) + t4.z;
        w.w = (e4.w - t4.w) + t4.w;
        ((float4*)(out + ((size_t)row * CCH + c) * VDIM))[m] = w;
        float s = 0.f, dx;
        dx = t4.x - e4.x; s = fmaf(dx, dx, s);
        dx = t4.y - e4.y; s = fmaf(dx, dx, s);
        dx = t4.z - e4.z; s = fmaf(dx, dx, s);
        dx = t4.w - e4.w; s = fmaf(dx, dx, s);
        s += __shfl_xor(s, 1, 64);
        s += __shfl_xor(s, 2, 64);
        s += __shfl_xor(s, 4, 64);
        s += __shfl_xor(s, 8, 64);
        if (m == 0) {
            const size_t idx = (size_t)row * CCH + c;
            out[base1 + idx] = s;                   // out1
            out[base2 + idx] = s;                   // out2 (identical in ref)
        }
    }
}

extern "C" void kernel_launch(void* const* d_in, const int* in_sizes, int n_in,
                              void* d_out, int out_size, void* d_ws, size_t ws_size,
                              hipStream_t stream) {
    const float* x   = (const float*)d_in[0];
    const float* emb = (const float*)d_in[1];
    float* out = (float*)d_out;
    vq_fused<<<dim3(NROW / 128, CCH), dim3(256), 0, stream>>>(x, emb, out);
}

// Round 7
// 92.622 us; speedup vs baseline: 3.7708x; 1.0796x over previous
//
#include <hip/hip_runtime.h>

// x (N,S,C,V) = (8,2048,4,64) fp32; embedding (C,K,V) = (4,512,64) fp32.
#define NROW 16384   // N*S
#define CCH  4
#define KCB  512
#define VDIM 64
#define KO   4096    // koct stride in ushorts = 512 codes * 8

typedef __attribute__((ext_vector_type(8))) short  short8;   // 8 x bf16
typedef __attribute__((ext_vector_type(4))) float  floatx4;  // MFMA acc

// round-to-nearest-even fp32 -> bf16 bits; rem = v - bf16(v)
__device__ inline unsigned short bf16h(float v, float* rem) {
    unsigned u = __float_as_uint(v);
    unsigned r = u + 0x7FFFu + ((u >> 16) & 1u);
    unsigned short h = (unsigned short)(r >> 16);
    *rem = v - __uint_as_float((unsigned)h << 16);
    return h;
}

// One block (512 thr, 8 waves) per CU; grid = (NROW/256, CCH) = (64,4) = 256.
// Whole channel codebook staged ONCE into LDS as bf16 hi/lo (128 KB) + e2
// (2 KB); single barrier; then a barrier-free K-loop: per 16-code tile
// 4 ds_read_b128 + 12 MFMA (hi/lo 3-product split, 2 row-groups, 4
// independent acc chains). argmin on d' = e2 - 2*xe (x2 row-constant drops
// out of argmin); exact fp32 epilogue from original x/emb.
// LDS layout bhi/blo[(koct*512 + code)*8 + j]: hot-loop reads are the
// round-6 measured-conflict-free pattern (256 B contiguous per quad).
__global__ __launch_bounds__(512, 1)
void vq_fused(const float* __restrict__ x, const float* __restrict__ emb,
              float* __restrict__ out) {
    extern __shared__ unsigned short smem[];
    unsigned short* bhi = smem;             // 32768 ushorts = 64 KB
    unsigned short* blo = smem + 32768;     // 64 KB
    float* e2s = (float*)(smem + 65536);    // 512 floats = 2 KB

    const int tid  = threadIdx.x;
    const int lane = tid & 63;
    const int m    = lane & 15;
    const int quad = lane >> 4;
    const int wave = tid >> 6;
    const int c    = blockIdx.y;
    const int rbase = blockIdx.x * 256 + wave * 32;

    const float* embc = emb + (size_t)c * (KCB * VDIM);

    // --- stage codebook: wave covers 64 codes; 16 coalesced 1KB wave-reads ---
    {
        const int cb = wave * 64;
#pragma unroll
        for (int j = 0; j < 16; ++j) {
            const int g = cb * 16 + j * 64 + lane;       // float4 index
            const float4 t = ((const float4*)embc)[g];
            const int code = cb + j * 4 + quad;          // 4 codes per read
            const int koct = m >> 1, half = m & 1;
            ushort4 h4, l4; float r, d;
            h4.x = bf16h(t.x, &r); l4.x = bf16h(r, &d);
            h4.y = bf16h(t.y, &r); l4.y = bf16h(r, &d);
            h4.z = bf16h(t.z, &r); l4.z = bf16h(r, &d);
            h4.w = bf16h(t.w, &r); l4.w = bf16h(r, &d);
            const int off = (koct * 512 + code) * 8 + half * 4;
            *(ushort4*)&bhi[off] = h4;
            *(ushort4*)&blo[off] = l4;
            // fused e2: reduce sum-of-squares over the 16 lanes of this code
            float s = 0.f;
            s = fmaf(t.x, t.x, s); s = fmaf(t.y, t.y, s);
            s = fmaf(t.z, t.z, s); s = fmaf(t.w, t.w, s);
            s += __shfl_xor(s, 1, 64);
            s += __shfl_xor(s, 2, 64);
            s += __shfl_xor(s, 4, 64);
            s += __shfl_xor(s, 8, 64);
            if (m == 0) e2s[code] = s;
        }
    }

    // --- A fragments: 2 row-groups x 2 k-halves, hi+lo, from fp32 x ---
    short8 ah[2][2], al[2][2];
#pragma unroll
    for (int g = 0; g < 2; ++g) {
        const int row = rbase + g * 16 + m;
        const float4* xr = (const float4*)(x + ((size_t)row * CCH + c) * VDIM);
#pragma unroll
        for (int h = 0; h < 2; ++h) {        // k = h*32 + quad*8 + j
            const float4 f0 = xr[h * 8 + quad * 2];
            const float4 f1 = xr[h * 8 + quad * 2 + 1];
            const float fv[8] = {f0.x, f0.y, f0.z, f0.w, f1.x, f1.y, f1.z, f1.w};
            short8 hh, ll;
#pragma unroll
            for (int j = 0; j < 8; ++j) {
                float r, d;
                hh[j] = (short)bf16h(fv[j], &r);
                ll[j] = (short)bf16h(r, &d);
            }
            ah[g][h] = hh; al[g][h] = ll;
        }
    }

    __syncthreads();   // the only barrier

    float bd[2][4]; int bkk[2][4];
#pragma unroll
    for (int g = 0; g < 2; ++g)
#pragma unroll
        for (int j = 0; j < 4; ++j) { bd[g][j] = 3.4e38f; bkk[g][j] = 0; }

#pragma unroll 4
    for (int t = 0; t < KCB / 16; ++t) {     // 32 tiles, ascending codes
        const int code = t * 16 + m;
        const unsigned short* ph = bhi + (size_t)(quad * 512 + code) * 8;
        const unsigned short* pl = blo + (size_t)(quad * 512 + code) * 8;
        const short8 bh0 = *(const short8*)ph;             // koct = quad
        const short8 bh1 = *(const short8*)(ph + 4 * KO);  // koct = quad+4
        const short8 bl0 = *(const short8*)pl;
        const short8 bl1 = *(const short8*)(pl + 4 * KO);
        const float e2v = e2s[code];

        // 4 independent chains: acch{0,1} depth-2, accm{0,1} depth-4
        floatx4 acch0 = {0.f,0.f,0.f,0.f}, acch1 = {0.f,0.f,0.f,0.f};
        floatx4 accm0 = {0.f,0.f,0.f,0.f}, accm1 = {0.f,0.f,0.f,0.f};
        acch0 = __builtin_amdgcn_mfma_f32_16x16x32_bf16(ah[0][0], bh0, acch0, 0, 0, 0);
        acch1 = __builtin_amdgcn_mfma_f32_16x16x32_bf16(ah[1][0], bh0, acch1, 0, 0, 0);
        accm0 = __builtin_amdgcn_mfma_f32_16x16x32_bf16(ah[0][0], bl0, accm0, 0, 0, 0);
        accm1 = __builtin_amdgcn_mfma_f32_16x16x32_bf16(ah[1][0], bl0, accm1, 0, 0, 0);
        acch0 = __builtin_amdgcn_mfma_f32_16x16x32_bf16(ah[0][1], bh1, acch0, 0, 0, 0);
        acch1 = __builtin_amdgcn_mfma_f32_16x16x32_bf16(ah[1][1], bh1, acch1, 0, 0, 0);
        accm0 = __builtin_amdgcn_mfma_f32_16x16x32_bf16(al[0][0], bh0, accm0, 0, 0, 0);
        accm1 = __builtin_amdgcn_mfma_f32_16x16x32_bf16(al[1][0], bh0, accm1, 0, 0, 0);
        accm0 = __builtin_amdgcn_mfma_f32_16x16x32_bf16(ah[0][1], bl1, accm0, 0, 0, 0);
        accm1 = __builtin_amdgcn_mfma_f32_16x16x32_bf16(ah[1][1], bl1, accm1, 0, 0, 0);
        accm0 = __builtin_amdgcn_mfma_f32_16x16x32_bf16(al[0][1], bh1, accm0, 0, 0, 0);
        accm1 = __builtin_amdgcn_mfma_f32_16x16x32_bf16(al[1][1], bh1, accm1, 0, 0, 0);

#pragma unroll
        for (int j = 0; j < 4; ++j) {
            const float d0 = fmaf(-2.0f, acch0[j] + accm0[j], e2v);
            const float d1 = fmaf(-2.0f, acch1[j] + accm1[j], e2v);
            if (d0 < bd[0][j]) { bd[0][j] = d0; bkk[0][j] = code; }
            if (d1 < bd[1][j]) { bd[1][j] = d1; bkk[1][j] = code; }
        }
    }

    // within-quad (16-lane) argmin; tie -> lower code (first-occurrence)
#pragma unroll
    for (int g = 0; g < 2; ++g)
#pragma unroll
    for (int j = 0; j < 4; ++j) {
        float d = bd[g][j]; int k = bkk[g][j];
#pragma unroll
        for (int mask = 1; mask < 16; mask <<= 1) {
            const float od = __shfl_xor(d, mask, 64);
            const int   ok = __shfl_xor(k, mask, 64);
            if (od < d || (od == d && ok < k)) { d = od; k = ok; }
        }
        bd[g][j] = d; bkk[g][j] = k;
    }

    // Epilogue: exact fp32 from original x and emb
    const size_t base1 = (size_t)NROW * CCH * VDIM;
    const size_t base2 = base1 + (size_t)NROW * CCH;
#pragma unroll
    for (int g = 0; g < 2; ++g)
#pragma unroll
    for (int j = 0; j < 4; ++j) {
        const int row  = rbase + g * 16 + quad * 4 + j;
        const int code = bkk[g][j];              // uniform within quad
        const float4 t4 = ((const float4*)(x + ((size_t)row * CCH + c) * VDIM))[m];
        const float4 e4 = ((const float4*)(embc + (size_t)code * VDIM))[m];
        float4 w;
        w.x = (e4.x - t4.x) + t4.x;              // out0 = (output - x) + x
        w.y = (e4.y - t4.y) + t4.y;
        w.z = (e4.z - t4.z) + t4.z;
        w.w = (e4.w - t4.w) + t4.w;
        ((float4*)(out + ((size_t)row * CCH + c) * VDIM))[m] = w;
        float s = 0.f, dx;
        dx = t4.x - e4.x; s = fmaf(dx, dx, s);
        dx = t4.y - e4.y; s = fmaf(dx, dx, s);
        dx = t4.z - e4.z; s = fmaf(dx, dx, s);
        dx = t4.w - e4.w; s = fmaf(dx, dx, s);
        s += __shfl_xor(s, 1, 64);
        s += __shfl_xor(s, 2, 64);
        s += __shfl_xor(s, 4, 64);
        s += __shfl_xor(s, 8, 64);
        if (m == 0) {
            const size_t idx = (size_t)row * CCH + c;
            out[base1 + idx] = s;                // out1
            out[base2 + idx] = s;                // out2 (identical in ref)
        }
    }
}

extern "C" void kernel_launch(void* const* d_in, const int* in_sizes, int n_in,
                              void* d_out, int out_size, void* d_ws, size_t ws_size,
                              hipStream_t stream) {
    const float* x   = (const float*)d_in[0];
    const float* emb = (const float*)d_in[1];
    float* out = (float*)d_out;
    const size_t lds_bytes = 65536u * 2u + 512u * 4u;   // 133120 B (of 160 KB)
    vq_fused<<<dim3(NROW / 256, CCH), dim3(512), lds_bytes, stream>>>(x, emb, out);
}

// Round 8
// 85.329 us; speedup vs baseline: 4.0931x; 1.0855x over previous
//
#include <hip/hip_runtime.h>

// x (N,S,C,V) = (8,2048,4,64) fp32; embedding (C,K,V) = (4,512,64) fp32.
#define NROW 16384   // N*S
#define CCH  4
#define KCB  512
#define VDIM 64

typedef __attribute__((ext_vector_type(8))) short  short8;   // 8 x bf16
typedef __attribute__((ext_vector_type(4))) float  floatx4;  // MFMA acc

// round-to-nearest-even fp32 -> bf16 bits; rem = v - bf16(v)
__device__ inline unsigned short bf16h(float v, float* rem) {
    unsigned u = __float_as_uint(v);
    unsigned r = u + 0x7FFFu + ((u >> 16) & 1u);
    unsigned short h = (unsigned short)(r >> 16);
    *rem = v - __uint_as_float((unsigned)h << 16);
    return h;
}
__device__ inline unsigned short bf16r(float v) {   // RNE round only
    unsigned u = __float_as_uint(v);
    return (unsigned short)((u + 0x7FFFu + ((u >> 16) & 1u)) >> 16);
}

// Block = 512 thr (8 waves); grid = (NROW/128, CCH) = 512 blocks = 2/CU.
// LDS = eh (64 KB, whole channel codebook bf16) + e2 (2 KB) = 66 KB ->
// 2 blocks/CU = 16 waves/CU (4/SIMD) for latency hiding. One barrier.
// Numerics: x split hi/lo bf16, e single bf16 -> xe err sigma ~6e-3 (e2 is
// exact fp32); argmin on d' = e2 - 2*xe (x2 row-constant drops out). Flips
// only at gap < ~2e-2: out1 err <= gap << 2.78, out0 err < 1.0 (codes in
// [0,1)). Exact fp32 epilogue from original x/emb.
// LDS layout: eh[(koct*512 + (code ^ koct))*8 + j] — XOR swizzle makes both
// the staging writes and the fragment reads bank-conflict-free.
__global__ __launch_bounds__(512, 4)
void vq_fused(const float* __restrict__ x, const float* __restrict__ emb,
              float* __restrict__ out) {
    extern __shared__ unsigned short smem[];
    unsigned short* eh = smem;              // 32768 ushorts = 64 KB
    float* e2s = (float*)(smem + 32768);    // 512 floats = 2 KB

    const int tid  = threadIdx.x;
    const int lane = tid & 63;
    const int m    = lane & 15;
    const int quad = lane >> 4;
    const int wave = tid >> 6;
    const int c    = blockIdx.y;
    const int rbase = blockIdx.x * 128 + wave * 16;

    const float* embc = emb + (size_t)c * (KCB * VDIM);

    // --- stage codebook: wave covers 64 codes; 16 coalesced 1KB wave-reads ---
    {
        const int cb = wave * 64;
        const int koct = m >> 1, half = m & 1;
#pragma unroll
        for (int j = 0; j < 16; ++j) {
            const int g = cb * 16 + j * 64 + lane;       // float4 index
            const float4 t = ((const float4*)embc)[g];
            const int code = cb + j * 4 + quad;          // this lane's code
            ushort4 h4;
            h4.x = bf16r(t.x); h4.y = bf16r(t.y);
            h4.z = bf16r(t.z); h4.w = bf16r(t.w);
            const int off = (koct * 512 + (code ^ koct)) * 8 + half * 4;
            *(ushort4*)&eh[off] = h4;
            // fused exact-fp32 e2: reduce over the 16 lanes of this code
            float s = 0.f;
            s = fmaf(t.x, t.x, s); s = fmaf(t.y, t.y, s);
            s = fmaf(t.z, t.z, s); s = fmaf(t.w, t.w, s);
            s += __shfl_xor(s, 1, 64);
            s += __shfl_xor(s, 2, 64);
            s += __shfl_xor(s, 4, 64);
            s += __shfl_xor(s, 8, 64);
            if (m == 0) e2s[code] = s;
        }
    }

    // --- A fragments: 1 row-group (16 rows), 2 k-halves, x hi/lo ---
    short8 ah[2], al[2];
    {
        const int row = rbase + m;
        const float4* xr = (const float4*)(x + ((size_t)row * CCH + c) * VDIM);
#pragma unroll
        for (int h = 0; h < 2; ++h) {        // k = h*32 + quad*8 + j
            const float4 f0 = xr[h * 8 + quad * 2];
            const float4 f1 = xr[h * 8 + quad * 2 + 1];
            const float fv[8] = {f0.x, f0.y, f0.z, f0.w, f1.x, f1.y, f1.z, f1.w};
            short8 hh, ll;
#pragma unroll
            for (int j = 0; j < 8; ++j) {
                float r, d;
                hh[j] = (short)bf16h(fv[j], &r);
                ll[j] = (short)bf16h(r, &d);
            }
            ah[h] = hh; al[h] = ll;
        }
    }

    __syncthreads();   // the only barrier

    float bd[4]; int bkk[4];
#pragma unroll
    for (int j = 0; j < 4; ++j) { bd[j] = 3.4e38f; bkk[j] = 0; }

    const int mq0 = m ^ quad;          // swizzled read indices (loop-invariant)
    const int mq1 = m ^ (quad + 4);

#pragma unroll 4
    for (int t = 0; t < KCB / 16; ++t) {     // 32 tiles, ascending codes
        const int code = t * 16 + m;
        const short8 bh0 = *(const short8*)&eh[( quad      * 512 + t * 16 + mq0) * 8];
        const short8 bh1 = *(const short8*)&eh[((quad + 4) * 512 + t * 16 + mq1) * 8];
        const float e2v = e2s[code];

        // 2 independent depth-2 chains: acc0 = xh.e, acc1 = xl.e
        floatx4 acc0 = {0.f,0.f,0.f,0.f}, acc1 = {0.f,0.f,0.f,0.f};
        acc0 = __builtin_amdgcn_mfma_f32_16x16x32_bf16(ah[0], bh0, acc0, 0, 0, 0);
        acc1 = __builtin_amdgcn_mfma_f32_16x16x32_bf16(al[0], bh0, acc1, 0, 0, 0);
        acc0 = __builtin_amdgcn_mfma_f32_16x16x32_bf16(ah[1], bh1, acc0, 0, 0, 0);
        acc1 = __builtin_amdgcn_mfma_f32_16x16x32_bf16(al[1], bh1, acc1, 0, 0, 0);

#pragma unroll
        for (int j = 0; j < 4; ++j) {
            const float d0 = fmaf(-2.0f, acc0[j] + acc1[j], e2v);
            if (d0 < bd[j]) { bd[j] = d0; bkk[j] = code; }  // strict < = first-min
        }
    }

    // within-quad (16-lane) argmin; tie -> lower code (first-occurrence)
#pragma unroll
    for (int j = 0; j < 4; ++j) {
        float d = bd[j]; int k = bkk[j];
#pragma unroll
        for (int mask = 1; mask < 16; mask <<= 1) {
            const float od = __shfl_xor(d, mask, 64);
            const int   ok = __shfl_xor(k, mask, 64);
            if (od < d || (od == d && ok < k)) { d = od; k = ok; }
        }
        bd[j] = d; bkk[j] = k;
    }

    // Epilogue: exact fp32 from original x and emb
    const size_t base1 = (size_t)NROW * CCH * VDIM;
    const size_t base2 = base1 + (size_t)NROW * CCH;
#pragma unroll
    for (int j = 0; j < 4; ++j) {
        const int row  = rbase + quad * 4 + j;
        const int code = bkk[j];                 // uniform within quad
        const float4 t4 = ((const float4*)(x + ((size_t)row * CCH + c) * VDIM))[m];
        const float4 e4 = ((const float4*)(embc + (size_t)code * VDIM))[m];
        float4 w;
        w.x = (e4.x - t4.x) + t4.x;              // out0 = (output - x) + x
        w.y = (e4.y - t4.y) + t4.y;
        w.z = (e4.z - t4.z) + t4.z;
        w.w = (e4.w - t4.w) + t4.w;
        ((float4*)(out + ((size_t)row * CCH + c) * VDIM))[m] = w;
        float s = 0.f, dx;
        dx = t4.x - e4.x; s = fmaf(dx, dx, s);
        dx = t4.y - e4.y; s = fmaf(dx, dx, s);
        dx = t4.z - e4.z; s = fmaf(dx, dx, s);
        dx = t4.w - e4.w; s = fmaf(dx, dx, s);
        s += __shfl_xor(s, 1, 64);
        s += __shfl_xor(s, 2, 64);
        s += __shfl_xor(s, 4, 64);
        s += __shfl_xor(s, 8, 64);
        if (m == 0) {
            const size_t idx = (size_t)row * CCH + c;
            out[base1 + idx] = s;                // out1
            out[base2 + idx] = s;                // out2 (identical in ref)
        }
    }
}

extern "C" void kernel_launch(void* const* d_in, const int* in_sizes, int n_in,
                              void* d_out, int out_size, void* d_ws, size_t ws_size,
                              hipStream_t stream) {
    const float* x   = (const float*)d_in[0];
    const float* emb = (const float*)d_in[1];
    float* out = (float*)d_out;
    const size_t lds_bytes = 65536u + 2048u;   // 67584 B -> 2 blocks/CU
    vq_fused<<<dim3(NROW / 128, CCH), dim3(512), lds_bytes, stream>>>(x, emb, out);
}